// Round 12
// baseline (144.927 us; speedup 1.0000x reference)
//
#include <hip/hip_runtime.h>

#define B_PATHS 32768
#define N_STEPS 50
#define H 64
#define NS 128             // table points per step; 50*128*4 = 25 KB LDS in sim
#define EV 4               // evals per table wave: VGPR ~100, no scratch spills
#define NTAB (N_STEPS * (NS / EV))   // 1600 table blocks
#define NSIM (B_PATHS / 64)          // 512 sim blocks
#define FLAG_MAGIC 0x5EED1DEAu       // != 0xAAAAAAAA poison, != 0

static __device__ __forceinline__ float gelu_f(float x) {
    // tanh-form GELU: max abs err vs exact-erf ~2e-4
    float x2 = x * x;
    float u  = x * fmaf(x2, 0.044715f * 0.7978845608f, 0.7978845608f);
    float e  = exp2f(u * -2.885390081777927f);   // e^{-2u}
    return x / (1.0f + e);
}

static __device__ __forceinline__ float sigmoid_f(float x) {
    float e = exp2f(x * -1.4426950408889634f);
    return 1.0f / (1.0f + e);
}

// Analytic per-step S envelope (covers 32k-path extremes ~4.2 sigma with 8-sigma bound).
static __device__ __forceinline__ void step_range(int i, float& lo, float& hi) {
    const float sd = 0.2f * 0.14142135623f;     // SIGMA * sqrt(DT)
    float w = fmaf(8.0f * sd, sqrtf((float)i), 0.05f);
    lo = 100.0f * expf(-w);
    hi = 100.0f * expf(w);
}

// Wave64 sum via DPP inclusive scan (VALU pipe) — AMDGPUAtomicOptimizer sequence:
// row_shr:1,2,4,8 then row_bcast:15, row_bcast:31; lane 63 holds the total.
// old=0 + bound_ctrl=1: invalid-source lanes read the additive identity.
template <int N>
static __device__ __forceinline__ void wave_sumN(float (&v)[N]) {
#define DPP_STAGE(CTRL)                                                                  \
    {                                                                                    \
        float t[N];                                                                      \
        _Pragma("unroll")                                                                \
        for (int e = 0; e < N; e++)                                                      \
            t[e] = __int_as_float(__builtin_amdgcn_update_dpp(                           \
                0, __float_as_int(v[e]), CTRL, 0xf, 0xf, true));                         \
        _Pragma("unroll")                                                                \
        for (int e = 0; e < N; e++) v[e] += t[e];                                        \
    }
    DPP_STAGE(0x111)   // row_shr:1
    DPP_STAGE(0x112)   // row_shr:2
    DPP_STAGE(0x114)   // row_shr:4
    DPP_STAGE(0x118)   // row_shr:8
    DPP_STAGE(0x142)   // row_bcast:15
    DPP_STAGE(0x143)   // row_bcast:31
#undef DPP_STAGE
    #pragma unroll
    for (int e = 0; e < N; e++)
        v[e] = __int_as_float(__builtin_amdgcn_readlane(__float_as_int(v[e]), 63));
}

// ---------------- fused single dispatch ----------------
// Blocks [0, NTAB): build table slice (weight-stationary, lane-per-neuron, DPP LN),
//   then release-store a magic flag (device scope).
// Blocks [NTAB, NTAB+NSIM): run phase A (dw preload + S-chain, table-independent),
//   batch-poll all flags, acquire-fence, stage table to LDS, run Y-chain.
// Deadlock-free: 25 KB LDS -> 6 blocks/CU -> 1536 slots; only 512 sim blocks can
// spin, >=1024 slots always available for the 1600 table blocks to drain through.
__global__ __launch_bounds__(64) void fused_kernel(
    const float* __restrict__ dw,
    const float* __restrict__ W1, const float* __restrict__ b1,
    const float* __restrict__ g1, const float* __restrict__ be1,
    const float* __restrict__ W2, const float* __restrict__ b2,
    const float* __restrict__ g2, const float* __restrict__ be2,
    const float* __restrict__ W3, const float* __restrict__ b3,
    const float* __restrict__ Y0,
    float* __restrict__ table, unsigned* __restrict__ flags,
    float* __restrict__ out)
{
    __shared__ float stab[N_STEPS * NS];   // 25 KB (table blocks use first 1 KB)

    int lane = threadIdx.x;

    if (blockIdx.x < NTAB) {
        // ================= table producer =================
        float* shg = stab;                 // EV*H = 256 floats
        int i  = blockIdx.x >> 5;          // step index (NS/EV = 32 blocks per step)
        int j0 = (blockIdx.x & 31) * EV;

        float w1a = W1[lane], w1b = W1[H + lane], bb1 = b1[lane];
        float gg1 = g1[lane], bbe1 = be1[lane];
        float bb2 = b2[lane], gg2 = g2[lane], bbe2 = be2[lane];
        float w3  = W3[lane];
        float b3s = b3[0];

        float w2c[H];                      // W2 column `lane`: coalesced, once
        #pragma unroll
        for (int k = 0; k < H; k++) w2c[k] = W2[k * H + lane];

        float lo, hi;
        step_range(i, lo, hi);
        float x1  = (float)i * 0.02f;      // == t_grid row value, bit-exact
        float dsg = (hi - lo) * (1.0f / (float)(NS - 1));

        // layer 1 + LN1 + gelu
        float h[EV], s1[EV];
        #pragma unroll
        for (int e = 0; e < EV; e++) {
            float s  = fmaf(dsg, (float)(j0 + e), lo);
            h[e] = fmaf(s * 0.01f, w1a, fmaf(x1, w1b, bb1));
            s1[e] = h[e];
        }
        wave_sumN<EV>(s1);
        float d[EV], vv[EV];
        #pragma unroll
        for (int e = 0; e < EV; e++) { d[e] = h[e] - s1[e] * (1.0f / H); vv[e] = d[e] * d[e]; }
        wave_sumN<EV>(vv);
        #pragma unroll
        for (int e = 0; e < EV; e++) {
            float rstd = rsqrtf(fmaf(vv[e], 1.0f / H, 1e-5f));
            shg[e * H + lane] = gelu_f(fmaf(d[e] * rstd, gg1, bbe1));
        }
        __syncthreads();                   // single wave: orders LDS write->read

        // layer 2 via wave-uniform b128 LDS broadcasts
        float acc[EV];
        #pragma unroll
        for (int e = 0; e < EV; e++) acc[e] = bb2;
        #pragma unroll
        for (int q = 0; q < H / 4; q++) {
            float4 hv[EV];
            #pragma unroll
            for (int e = 0; e < EV; e++) hv[e] = ((const float4*)(shg + e * H))[q];
            #pragma unroll
            for (int e = 0; e < EV; e++) {
                acc[e] = fmaf(hv[e].x, w2c[4 * q + 0], acc[e]);
                acc[e] = fmaf(hv[e].y, w2c[4 * q + 1], acc[e]);
                acc[e] = fmaf(hv[e].z, w2c[4 * q + 2], acc[e]);
                acc[e] = fmaf(hv[e].w, w2c[4 * q + 3], acc[e]);
            }
        }

        // LN2 + gelu + layer 3 + sigmoid
        float s2[EV];
        #pragma unroll
        for (int e = 0; e < EV; e++) s2[e] = acc[e];
        wave_sumN<EV>(s2);
        float d2[EV], v2[EV];
        #pragma unroll
        for (int e = 0; e < EV; e++) { d2[e] = acc[e] - s2[e] * (1.0f / H); v2[e] = d2[e] * d2[e]; }
        wave_sumN<EV>(v2);
        float zf[EV];
        #pragma unroll
        for (int e = 0; e < EV; e++) {
            float rstd = rsqrtf(fmaf(v2[e], 1.0f / H, 1e-5f));
            zf[e] = gelu_f(fmaf(d2[e] * rstd, gg2, bbe2)) * w3;
        }
        wave_sumN<EV>(zf);

        float zo = sigmoid_f(zf[0] + b3s);
        #pragma unroll
        for (int e = 1; e < EV; e++) {
            float z = sigmoid_f(zf[e] + b3s);
            zo = (lane == e) ? z : zo;
        }
        if (lane < EV) table[i * NS + j0 + lane] = zo;

        __threadfence();                   // drain stores device-wide (wave-level waitcnt+wb)
        if (lane == 0)
            __hip_atomic_store(&flags[blockIdx.x], FLAG_MAGIC,
                               __ATOMIC_RELEASE, __HIP_MEMORY_SCOPE_AGENT);
    } else {
        // ================= sim consumer =================
        int p = (blockIdx.x - NTAB) * 64 + lane;
        const float rdt = 0.05f * 0.02f;
        const float nsm1 = (float)(NS - 1);

        // phase A first: table-independent (overlaps table producers)
        float dwl[N_STEPS];
        const float2* dw2 = (const float2*)(dw + p * N_STEPS);
        #pragma unroll
        for (int q = 0; q < N_STEPS / 2; q++) {
            float2 v = dw2[q];
            dwl[2 * q]     = v.x;
            dwl[2 * q + 1] = v.y;
        }

        float Sarr[N_STEPS + 1];
        float u[N_STEPS];
        Sarr[0] = 100.0f;
        #pragma unroll
        for (int i = 0; i < N_STEPS; i++) {
            float S = Sarr[i];
            float lo, hi;
            step_range(i, lo, hi);
            float uu = (S - lo) * (nsm1 / (hi - lo));
            u[i] = fminf(fmaxf(uu, 0.0f), nsm1);
            float dS = S * fmaf(0.2f, dwl[i], rdt);
            Sarr[i + 1] = S + dS;
        }

        // batch-poll all NTAB flags: 25 independent relaxed loads per lane per round
        bool alldone;
        do {
            bool ok = true;
            #pragma unroll
            for (int q = 0; q < NTAB / 64; q++)
                ok &= (__hip_atomic_load(&flags[q * 64 + lane],
                                         __ATOMIC_RELAXED, __HIP_MEMORY_SCOPE_AGENT)
                       == FLAG_MAGIC);
            alldone = __all(ok);
            if (!alldone) __builtin_amdgcn_s_sleep(8);
        } while (!alldone);
        __threadfence();                   // acquire: invalidate stale L1/L2 lines

        // stage table to LDS (25 float4 per lane)
        const float4* tg = (const float4*)table;
        float4* ts = (float4*)stab;
        #pragma unroll
        for (int q = 0; q < (N_STEPS * NS / 4) / 64; q++)
            ts[q * 64 + lane] = tg[q * 64 + lane];
        __syncthreads();

        // phase B: Y-chain with LDS gathers (addresses all ready)
        float Y = Y0[0];
        #pragma unroll
        for (int i = 0; i < N_STEPS; i++) {
            float uu = u[i];
            int jj = (int)uu;
            jj = min(jj, NS - 2);
            float f = uu - (float)jj;
            const float* row = stab + i * NS;
            float z0 = row[jj];
            float z1 = row[jj + 1];
            float z = fmaf(f, z1 - z0, z0);
            float S  = Sarr[i];
            float dS = Sarr[i + 1] - S;
            Y = Y + rdt * (Y - z * S) + z * dS;
        }
        out[p] = Y;
        out[B_PATHS + p] = Sarr[N_STEPS];
    }
}

extern "C" void kernel_launch(void* const* d_in, const int* in_sizes, int n_in,
                              void* d_out, int out_size, void* d_ws, size_t ws_size,
                              hipStream_t stream)
{
    const float* dw  = (const float*)d_in[0];
    const float* W1  = (const float*)d_in[2];
    const float* b1  = (const float*)d_in[3];
    const float* g1  = (const float*)d_in[4];
    const float* be1 = (const float*)d_in[5];
    const float* W2  = (const float*)d_in[6];
    const float* b2  = (const float*)d_in[7];
    const float* g2  = (const float*)d_in[8];
    const float* be2 = (const float*)d_in[9];
    const float* W3  = (const float*)d_in[10];
    const float* b3  = (const float*)d_in[11];
    const float* Y0  = (const float*)d_in[12];
    float* out = (float*)d_out;

    float*    table = (float*)d_ws;                       // 25600 B
    unsigned* flags = (unsigned*)((char*)d_ws + 32768);   // 6400 B; poisoned 0xAA != MAGIC

    fused_kernel<<<NTAB + NSIM, 64, 0, stream>>>(
        dw, W1, b1, g1, be1, W2, b2, g2, be2, W3, b3, Y0, table, flags, out);
}

// Round 13
// 89.527 us; speedup vs baseline: 1.6188x; 1.6188x over previous
//
#include <hip/hip_runtime.h>

#define B_PATHS 32768
#define N_STEPS 50
#define H 64
#define NS 128             // table points per step; 50*128*4 = 25 KB LDS in sim.
                           // absmax interp-insensitive NS=1024..128 (tanh-GELU systematic
                           // dominates); NS=128 interp err ~1e-3 << 4.92 threshold.
#define EV 4               // evals per wave: VGPR ~100, no scratch spills (r7 lesson)

static __device__ __forceinline__ float gelu_f(float x) {
    // tanh-form GELU: max abs err vs exact-erf ~2e-4
    float x2 = x * x;
    float u  = x * fmaf(x2, 0.044715f * 0.7978845608f, 0.7978845608f);
    float e  = exp2f(u * -2.885390081777927f);   // e^{-2u}
    return x / (1.0f + e);
}

static __device__ __forceinline__ float sigmoid_f(float x) {
    float e = exp2f(x * -1.4426950408889634f);
    return 1.0f / (1.0f + e);
}

// Analytic per-step S envelope (covers 32k-path extremes ~4.2 sigma with 8-sigma bound).
static __device__ __forceinline__ void step_range(int i, float& lo, float& hi) {
    const float sd = 0.2f * 0.14142135623f;     // SIGMA * sqrt(DT)
    float w = fmaf(8.0f * sd, sqrtf((float)i), 0.05f);
    lo = 100.0f * expf(-w);
    hi = 100.0f * expf(w);
}

// Wave64 sum via DPP inclusive scan (VALU pipe) — AMDGPUAtomicOptimizer sequence:
// row_shr:1,2,4,8 then row_bcast:15, row_bcast:31; lane 63 holds the total.
// old=0 + bound_ctrl=1: invalid-source lanes read the additive identity.
template <int N>
static __device__ __forceinline__ void wave_sumN(float (&v)[N]) {
#define DPP_STAGE(CTRL)                                                                  \
    {                                                                                    \
        float t[N];                                                                      \
        _Pragma("unroll")                                                                \
        for (int e = 0; e < N; e++)                                                      \
            t[e] = __int_as_float(__builtin_amdgcn_update_dpp(                           \
                0, __float_as_int(v[e]), CTRL, 0xf, 0xf, true));                         \
        _Pragma("unroll")                                                                \
        for (int e = 0; e < N; e++) v[e] += t[e];                                        \
    }
    DPP_STAGE(0x111)   // row_shr:1
    DPP_STAGE(0x112)   // row_shr:2
    DPP_STAGE(0x114)   // row_shr:4
    DPP_STAGE(0x118)   // row_shr:8
    DPP_STAGE(0x142)   // row_bcast:15
    DPP_STAGE(0x143)   // row_bcast:31
#undef DPP_STAGE
    #pragma unroll
    for (int e = 0; e < N; e++)
        v[e] = __int_as_float(__builtin_amdgcn_readlane(__float_as_int(v[e]), 63));
}

// ---------------- pass 1: tabulate zeta_i(s), weight-stationary + DPP ----------------
// Lane n owns neuron n; W2 column n in 64 VGPRs (loaded once per wave, L2-hot after
// the first blocks). LN reductions on the VALU pipe (DPP). Layer-2 hg broadcast via
// LDS: 1 ds_write + 16 wave-uniform ds_read_b128 per eval (same-address broadcast).
// 50*(128/4) = 1600 blocks of one wave.
__global__ __launch_bounds__(64) void table_kernel(
    const float* __restrict__ W1, const float* __restrict__ b1,
    const float* __restrict__ g1, const float* __restrict__ be1,
    const float* __restrict__ W2, const float* __restrict__ b2,
    const float* __restrict__ g2, const float* __restrict__ be2,
    const float* __restrict__ W3, const float* __restrict__ b3,
    float* __restrict__ table)
{
    __shared__ float shg[EV * H];        // 1 KB

    int lane = threadIdx.x;
    int i  = blockIdx.x >> 5;            // step index (32 blocks per step, NS/EV=32)
    int j0 = (blockIdx.x & 31) * EV;     // first table point of this wave

    float w1a = W1[lane], w1b = W1[H + lane], bb1 = b1[lane];
    float gg1 = g1[lane], bbe1 = be1[lane];
    float bb2 = b2[lane], gg2 = g2[lane], bbe2 = be2[lane];
    float w3  = W3[lane];
    float b3s = b3[0];

    float w2c[H];                        // W2 column `lane`: coalesced, once
    #pragma unroll
    for (int k = 0; k < H; k++) w2c[k] = W2[k * H + lane];

    float lo, hi;
    step_range(i, lo, hi);
    float x1  = (float)i * 0.02f;        // == t_grid row value, bit-exact
    float dsg = (hi - lo) * (1.0f / (float)(NS - 1));

    // ---- layer 1 + LN1 + gelu ----
    float h[EV], s1[EV];
    #pragma unroll
    for (int e = 0; e < EV; e++) {
        float s  = fmaf(dsg, (float)(j0 + e), lo);
        h[e] = fmaf(s * 0.01f, w1a, fmaf(x1, w1b, bb1));
        s1[e] = h[e];
    }
    wave_sumN<EV>(s1);
    float d[EV], vv[EV];
    #pragma unroll
    for (int e = 0; e < EV; e++) { d[e] = h[e] - s1[e] * (1.0f / H); vv[e] = d[e] * d[e]; }
    wave_sumN<EV>(vv);
    #pragma unroll
    for (int e = 0; e < EV; e++) {
        float rstd = rsqrtf(fmaf(vv[e], 1.0f / H, 1e-5f));
        shg[e * H + lane] = gelu_f(fmaf(d[e] * rstd, gg1, bbe1));
    }
    __syncthreads();                     // single wave: just orders LDS write->read

    // ---- layer 2: acc[e] = sum_k hg[e][k] * w2c[k], hg via wave-uniform b128 reads ----
    float acc[EV];
    #pragma unroll
    for (int e = 0; e < EV; e++) acc[e] = bb2;
    #pragma unroll
    for (int q = 0; q < H / 4; q++) {
        float4 hv[EV];
        #pragma unroll
        for (int e = 0; e < EV; e++) hv[e] = ((const float4*)(shg + e * H))[q];
        #pragma unroll
        for (int e = 0; e < EV; e++) {
            acc[e] = fmaf(hv[e].x, w2c[4 * q + 0], acc[e]);
            acc[e] = fmaf(hv[e].y, w2c[4 * q + 1], acc[e]);
            acc[e] = fmaf(hv[e].z, w2c[4 * q + 2], acc[e]);
            acc[e] = fmaf(hv[e].w, w2c[4 * q + 3], acc[e]);
        }
    }

    // ---- LN2 + gelu + layer 3 + sigmoid ----
    float s2[EV];
    #pragma unroll
    for (int e = 0; e < EV; e++) s2[e] = acc[e];
    wave_sumN<EV>(s2);
    float d2[EV], v2[EV];
    #pragma unroll
    for (int e = 0; e < EV; e++) { d2[e] = acc[e] - s2[e] * (1.0f / H); v2[e] = d2[e] * d2[e]; }
    wave_sumN<EV>(v2);
    float zf[EV];
    #pragma unroll
    for (int e = 0; e < EV; e++) {
        float rstd = rsqrtf(fmaf(v2[e], 1.0f / H, 1e-5f));
        zf[e] = gelu_f(fmaf(d2[e] * rstd, gg2, bbe2)) * w3;
    }
    wave_sumN<EV>(zf);

    // lane e stores eval e (select chain avoids runtime-indexed register array)
    float zo = sigmoid_f(zf[0] + b3s);
    #pragma unroll
    for (int e = 1; e < EV; e++) {
        float z = sigmoid_f(zf[e] + b3s);
        zo = (lane == e) ? z : zo;
    }
    if (lane < EV) table[i * NS + j0 + lane] = zo;
}

// ---------------- pass 2: simulate paths, table gathered from LDS ----------------
// 512 blocks x 64 threads. Staging issued first, then dw preload + S-chain run
// UNDER the staging latency; __syncthreads only before the Y-chain needs the table.
__global__ __launch_bounds__(64) void sim_kernel(const float* __restrict__ dw,
                                                 const float* __restrict__ table,
                                                 const float* __restrict__ Y0,
                                                 float* __restrict__ out)
{
    __shared__ float stab[N_STEPS * NS];   // 25 KB

    int lane = threadIdx.x;

    // issue staging (25 float4 per lane); latency hides under phase A below
    const float4* tg = (const float4*)table;
    float4* ts = (float4*)stab;
    #pragma unroll
    for (int q = 0; q < (N_STEPS * NS / 4) / 64; q++)   // 25
        ts[q * 64 + lane] = tg[q * 64 + lane];

    int p = blockIdx.x * 64 + lane;
    const float rdt = 0.05f * 0.02f;
    const float nsm1 = (float)(NS - 1);

    float dwl[N_STEPS];
    const float2* dw2 = (const float2*)(dw + p * N_STEPS);
    #pragma unroll
    for (int q = 0; q < N_STEPS / 2; q++) {
        float2 v = dw2[q];
        dwl[2 * q]     = v.x;
        dwl[2 * q + 1] = v.y;
    }

    // phase A: S-chain + interp coordinates (envelope math is off-chain ILP)
    float Sarr[N_STEPS + 1];
    float u[N_STEPS];
    Sarr[0] = 100.0f;
    #pragma unroll
    for (int i = 0; i < N_STEPS; i++) {
        float S = Sarr[i];
        float lo, hi;
        step_range(i, lo, hi);
        float uu = (S - lo) * (nsm1 / (hi - lo));
        u[i] = fminf(fmaxf(uu, 0.0f), nsm1);
        float dS = S * fmaf(0.2f, dwl[i], rdt);
        Sarr[i + 1] = S + dS;
    }

    __syncthreads();                     // staging complete; table needed from here

    // phase B: Y-chain with LDS gathers (addresses all ready)
    float Y = Y0[0];
    #pragma unroll
    for (int i = 0; i < N_STEPS; i++) {
        float uu = u[i];
        int jj = (int)uu;
        jj = min(jj, NS - 2);
        float f = uu - (float)jj;
        const float* row = stab + i * NS;
        float z0 = row[jj];
        float z1 = row[jj + 1];
        float z = fmaf(f, z1 - z0, z0);
        float S  = Sarr[i];
        float dS = Sarr[i + 1] - S;
        Y = Y + rdt * (Y - z * S) + z * dS;
    }
    out[p] = Y;
    out[B_PATHS + p] = Sarr[N_STEPS];
}

extern "C" void kernel_launch(void* const* d_in, const int* in_sizes, int n_in,
                              void* d_out, int out_size, void* d_ws, size_t ws_size,
                              hipStream_t stream)
{
    const float* dw  = (const float*)d_in[0];
    const float* W1  = (const float*)d_in[2];
    const float* b1  = (const float*)d_in[3];
    const float* g1  = (const float*)d_in[4];
    const float* be1 = (const float*)d_in[5];
    const float* W2  = (const float*)d_in[6];
    const float* b2  = (const float*)d_in[7];
    const float* g2  = (const float*)d_in[8];
    const float* be2 = (const float*)d_in[9];
    const float* W3  = (const float*)d_in[10];
    const float* b3  = (const float*)d_in[11];
    const float* Y0  = (const float*)d_in[12];
    float* out   = (float*)d_out;
    float* table = (float*)d_ws;           // 25 KB used

    table_kernel<<<N_STEPS * (NS / EV), 64, 0, stream>>>(
        W1, b1, g1, be1, W2, b2, g2, be2, W3, b3, table);
    sim_kernel<<<B_PATHS / 64, 64, 0, stream>>>(dw, table, Y0, out);
}